// Round 7
// baseline (1636.004 us; speedup 1.0000x reference)
//
#include <hip/hip_runtime.h>
#include <stdint.h>

typedef __bf16 bf16;
typedef __bf16 bf16x8 __attribute__((ext_vector_type(8)));
typedef float  f32x4  __attribute__((ext_vector_type(4)));
typedef unsigned int u32;

// ---------------- workspace layout (bytes), total = 134,217,728 (128 MiB) ----------
// Phase g1 (search, fused 16-batch conv):
//   A16_hi [16][34][34][1024] bf16 : 0          37,879,808
//   A16_lo                         : 37,879,808 37,879,808  (ends 75,759,616)
//   W1_hi                          : 75,759,616 14,155,776
//   W1_lo                          : 89,915,392 14,155,776  (ends 104,071,168)
//   qkeyT [16][1024px][256c] u32   : 117,440,512 16,777,216 (ends 134,217,728) LIVE->scores
// Phase g0 (temp, 2 x 8-batch conv):
//   A8_hi  [8][34][34][1024] bf16  : 0          18,939,904
//   A8_lo                          : 18,939,904 18,939,904  (ends 37,879,808)
//   W0_hi                          : 37,879,808 14,155,776
//   W0_lo                          : 52,035,584 14,155,776  (ends 66,191,360)
//   mkeyT [16][1024px][256c] u32   : 67,108,864 16,777,216  LIVE->scores
//   mval  [16][512c][1024m] u32    : 83,886,080 33,554,432  (ends 117,440,512) LIVE->memv
// Attention phase:
//   wattn [16][1024q][1024m] f32   : 0          67,108,864  (overlays dead A/W)
// Zero pass covers 32 planes (16 hi + 16 lo of A16); g0's A8 planes are a byte-
// identical subset (plane stride 2,367,488 B), so one zeroing serves both phases.
#define OFF_A16HI 0ull
#define OFF_A16LO 37879808ull
#define OFF_A8HI  0ull
#define OFF_A8LO  18939904ull
#define OFF_W1HI  75759616ull
#define OFF_W1LO  89915392ull
#define OFF_W0HI  37879808ull
#define OFF_W0LO  52035584ull
#define OFF_MKEYT 67108864ull
#define OFF_MVAL  83886080ull
#define OFF_QKEYT 117440512ull
#define OFF_WATTN 0ull

__device__ __forceinline__ void split(float v, bf16& h, bf16& l) {
    h = (bf16)v;
    l = (bf16)(v - (float)h);
}

__device__ __forceinline__ u32 packsplit(float v) {
    bf16 h = (bf16)v;
    bf16 l = (bf16)(v - (float)h);
    unsigned short hu = __builtin_bit_cast(unsigned short, h);
    unsigned short lu = __builtin_bit_cast(unsigned short, l);
    return (u32)hu | ((u32)lu << 16);
}

// de-interleave 4 packed c's -> 4 hi ushorts + 4 lo ushorts
__device__ __forceinline__ void deint4(const uint4 v, uint2& h, uint2& l) {
    h.x = (v.x & 0xffffu) | (v.y << 16);
    h.y = (v.z & 0xffffu) | (v.w << 16);
    l.x = (v.x >> 16) | (v.y & 0xffff0000u);
    l.y = (v.z >> 16) | (v.w & 0xffff0000u);
}

// ---------------- weight transform: fragment-major split ----------------
__global__ __launch_bounds__(256) void k_wt(const float* __restrict__ wk,
                                            const float* __restrict__ wv,
                                            bf16* __restrict__ Wh, bf16* __restrict__ Wl) {
    size_t id = (size_t)blockIdx.x * 256 + threadIdx.x;   // < 7,077,888
    int e = (int)(id & 7);
    size_t t = id >> 3;
    int mm = (int)(t % 96); t /= 96;
    int coff = (int)(t & 3); t >>= 2;
    int cch = (int)(t & 31); t >>= 5;
    int r = (int)(t % 9);
    int mt = (int)(t / 9);
    int m = mt * 96 + mm;
    int c = cch * 32 + coff * 8 + e;
    float v = (m < 256) ? wk[((size_t)m * 1024 + c) * 9 + r]
                        : wv[((size_t)(m - 256) * 1024 + c) * 9 + r];
    bf16 h, l;
    split(v, h, l);
    Wh[id] = h; Wl[id] = l;
}

// ---------------- zero padded borders of 32 A-planes (once) ----------------
__global__ __launch_bounds__(256) void k_zero(bf16* __restrict__ A) {
    int id = blockIdx.x * 256 + threadIdx.x;   // < 540,672
    int oct = id & 127;
    int t = id >> 7;
    int pos = t % 132; t /= 132;               // t = plane 0..31
    int yy, xx;
    if (pos < 34)       { yy = 0;  xx = pos; }
    else if (pos < 68)  { yy = 33; xx = pos - 34; }
    else if (pos < 100) { yy = pos - 68 + 1;  xx = 0; }
    else                { yy = pos - 100 + 1; xx = 33; }
    size_t off = (((size_t)t * 1156) + yy * 34 + xx) * 1024 + (size_t)oct * 8;
    *(uint4*)(A + off) = make_uint4(0u, 0u, 0u, 0u);
}

// ---------------- NCHW f32 -> padded channel-last bf16 hi/lo ----------------
__global__ __launch_bounds__(256) void k_transpose(const float* __restrict__ src,
                                                   bf16* __restrict__ Ah, bf16* __restrict__ Al) {
    int pt = blockIdx.x, ct = blockIdx.y, bl = blockIdx.z;
    __shared__ float tile[64][68];
    int t = threadIdx.x;
    #pragma unroll
    for (int k = 0; k < 4; ++k) {
        int idx = t + 256 * k;          // 0..1023
        int c = idx >> 4, f4 = idx & 15;
        float4 v = *(const float4*)(src + ((size_t)bl * 1024 + ct * 64 + c) * 1024 + pt * 64 + f4 * 4);
        *(float4*)&tile[c][f4 * 4] = v;
    }
    __syncthreads();
    #pragma unroll
    for (int k = 0; k < 2; ++k) {
        int s = t + 256 * k;            // 0..511
        int px = s >> 3, oct = s & 7;
        bf16x8 vh, vl;
        #pragma unroll
        for (int e = 0; e < 8; ++e) {
            bf16 h, l;
            split(tile[oct * 8 + e][px], h, l);
            vh[e] = h; vl[e] = l;
        }
        int pxg = pt * 64 + px;
        int yy = (pxg >> 5) + 1, xx = (pxg & 31) + 1;
        size_t off = (((size_t)bl * 34 + yy) * 34 + xx) * 1024 + ct * 64 + oct * 8;
        *(bf16x8*)(Ah + off) = vh;
        *(bf16x8*)(Al + off) = vl;
    }
}

#define XS_STRIDE 40   // 32 c used + 8 pad: 80B px-stride keeps 16B align, 2-way-max banks

// ---------------- conv g1 (search), fused 16 batches, j=4 ----------------
// 1024 blocks of 256 thr (1-D grid, mt = id&7 so each XCD holds one mt's weights).
// Block: 96 ch x 128 px; wave tile 48x64 (weight frags amortized over 64 px).
// keys -> qkeyT packed px-major; values -> f32 d_out channels 512..1023.
#define XS_H6 (6 * 34 * XS_STRIDE)
__global__ __launch_bounds__(256) void k_conv16(const bf16* __restrict__ Ah, const bf16* __restrict__ Al,
                                                const bf16* __restrict__ Wh, const bf16* __restrict__ Wl,
                                                const float* __restrict__ biask, const float* __restrict__ biasv,
                                                u32* __restrict__ keyT, float* __restrict__ valf) {
    int id = blockIdx.x;
    int mt = id & 7;
    int r2 = id >> 3;            // 0..127
    int bl = r2 >> 3;            // 0..15 (batch)
    int rg = r2 & 7;             // 0..7 (128-px group)
    int y0 = rg * 4;
    int b = bl;

    __shared__ bf16 Xs[2 * XS_H6];   // 32,640 B -> 4 blocks/CU

    int tid = threadIdx.x;
    int w = tid >> 6, l = tid & 63;
    int wm = (w & 1) * 48, wn = (w >> 1) * 64;
    int lm = l & 15, lq = l >> 4;
    int koff = lq * 8;

    f32x4 acc[3][4] = {};

    const size_t Abase = ((size_t)bl * 34 + y0) * 34 * 1024;
    const size_t wlane = (size_t)lq * 768 + (size_t)lm * 8;

    // hoisted per-thread staging addresses (c-chunk-invariant)
    const bf16* gsrc[7];
    int lidx[7];
    #pragma unroll
    for (int it = 0; it < 7; ++it) {
        int s = tid + 256 * it;
        if (s < 1632) {
            int hl = s >= 816;
            int r816 = s - hl * 816;
            int row = r816 / 136;
            int rr = r816 - row * 136;
            int px = rr >> 2, oct = rr & 3;
            const bf16* base = hl ? Al : Ah;
            gsrc[it] = base + Abase + ((size_t)row * 34 + px) * 1024 + oct * 8;
            lidx[it] = ((hl * 6 + row) * 34 + px) * XS_STRIDE + oct * 8;
        } else { gsrc[it] = nullptr; lidx[it] = -1; }
    }

    for (int cch = 0; cch < 32; ++cch) {
        int c0 = cch * 32;
        bf16x8 xv[7];
        #pragma unroll
        for (int it = 0; it < 7; ++it)
            if (lidx[it] >= 0) xv[it] = *(const bf16x8*)(gsrc[it] + c0);
        __syncthreads();                // previous iteration's LDS reads complete
        #pragma unroll
        for (int it = 0; it < 7; ++it)
            if (lidx[it] >= 0) *(bf16x8*)&Xs[lidx[it]] = xv[it];
        __syncthreads();                // LDS visible

        #pragma unroll
        for (int r = 0; r < 9; ++r) {
            int dy = r / 3, dx = r % 3;
            size_t wblk = (((size_t)mt * 9 + r) * 32 + cch) * 3072 + wlane;
            bf16x8 ah[3], al[3];
            #pragma unroll
            for (int i = 0; i < 3; ++i) {
                size_t o = wblk + (size_t)(wm + i * 16) * 8;
                ah[i] = *(const bf16x8*)(Wh + o);
                al[i] = *(const bf16x8*)(Wl + o);
            }
            #pragma unroll
            for (int j = 0; j < 4; ++j) {
                int n = wn + j * 16 + lm;
                int lbase = (((n >> 5) + dy) * 34 + (n & 31) + dx) * XS_STRIDE + koff;
                bf16x8 bh  = *(const bf16x8*)&Xs[lbase];
                bf16x8 blo = *(const bf16x8*)&Xs[XS_H6 + lbase];
                #pragma unroll
                for (int i = 0; i < 3; ++i) {
                    acc[i][j] = __builtin_amdgcn_mfma_f32_16x16x32_bf16(ah[i], bh,  acc[i][j], 0, 0, 0);
                    acc[i][j] = __builtin_amdgcn_mfma_f32_16x16x32_bf16(ah[i], blo, acc[i][j], 0, 0, 0);
                    acc[i][j] = __builtin_amdgcn_mfma_f32_16x16x32_bf16(al[i], bh,  acc[i][j], 0, 0, 0);
                }
            }
        }
    }

    // ---- epilogue: C/D layout col=lane&15, row=(lane>>4)*4+reg ----
    int col = lm, rowb = lq * 4;
    #pragma unroll
    for (int i = 0; i < 3; ++i) {
        int ch4 = mt * 96 + wm + i * 16 + rowb;
        #pragma unroll
        for (int j = 0; j < 4; ++j) {
            int px = rg * 128 + wn + j * 16 + col;
            if (ch4 < 256) {
                u32 p0 = packsplit(acc[i][j][0] + biask[ch4 + 0]);
                u32 p1 = packsplit(acc[i][j][1] + biask[ch4 + 1]);
                u32 p2 = packsplit(acc[i][j][2] + biask[ch4 + 2]);
                u32 p3 = packsplit(acc[i][j][3] + biask[ch4 + 3]);
                *(uint4*)(keyT + ((size_t)b * 1024 + px) * 256 + ch4) = make_uint4(p0, p1, p2, p3);
            } else {
                int cv = ch4 - 256;
                #pragma unroll
                for (int e = 0; e < 4; ++e)
                    valf[((size_t)b * 1024 + 512 + cv + e) * 1024 + px] = acc[i][j][e] + biasv[cv + e];
            }
        }
    }
}

// ---------------- conv g0 (temp), 8 batches, j=2 (round-6 proven) ----------------
// 1024 blocks 1-D (mt = id&7 swizzle); block 96 ch x 64 px; staging addrs hoisted.
// keys -> mkeyT packed px-major; values -> mval packed c-major.
#define XS_H4 (4 * 34 * XS_STRIDE)
__global__ __launch_bounds__(256) void k_conv8(const bf16* __restrict__ Ah, const bf16* __restrict__ Al,
                                               const bf16* __restrict__ Wh, const bf16* __restrict__ Wl,
                                               const float* __restrict__ biask, const float* __restrict__ biasv,
                                               u32* __restrict__ keyT, u32* __restrict__ valp, int bglob) {
    int id = blockIdx.x;
    int mt = id & 7;
    int r2 = id >> 3;            // 0..127
    int bl = r2 >> 4;            // 0..7
    int rg = r2 & 15;            // 0..15 (64-px group)
    int y0 = rg * 2;
    int b = bglob + bl;

    __shared__ bf16 Xs[2 * XS_H4];   // 21,760 B

    int tid = threadIdx.x;
    int w = tid >> 6, l = tid & 63;
    int wm = (w & 1) * 48, wn = (w >> 1) * 32;
    int lm = l & 15, lq = l >> 4;
    int koff = lq * 8;

    f32x4 acc[3][2] = {};

    const size_t Abase = ((size_t)bl * 34 + y0) * 34 * 1024;
    const size_t wlane = (size_t)lq * 768 + (size_t)lm * 8;

    const bf16* gsrc[5];
    int lidx[5];
    #pragma unroll
    for (int it = 0; it < 5; ++it) {
        int s = tid + 256 * it;
        if (s < 1088) {
            int hl = s >= 544;
            int r544 = s - hl * 544;
            int row = r544 / 136;
            int rr = r544 - row * 136;
            int px = rr >> 2, oct = rr & 3;
            const bf16* base = hl ? Al : Ah;
            gsrc[it] = base + Abase + ((size_t)row * 34 + px) * 1024 + oct * 8;
            lidx[it] = ((hl * 4 + row) * 34 + px) * XS_STRIDE + oct * 8;
        } else { gsrc[it] = nullptr; lidx[it] = -1; }
    }

    for (int cch = 0; cch < 32; ++cch) {
        int c0 = cch * 32;
        bf16x8 xv[5];
        #pragma unroll
        for (int it = 0; it < 5; ++it)
            if (lidx[it] >= 0) xv[it] = *(const bf16x8*)(gsrc[it] + c0);
        __syncthreads();
        #pragma unroll
        for (int it = 0; it < 5; ++it)
            if (lidx[it] >= 0) *(bf16x8*)&Xs[lidx[it]] = xv[it];
        __syncthreads();

        #pragma unroll
        for (int r = 0; r < 9; ++r) {
            int dy = r / 3, dx = r % 3;
            size_t wblk = (((size_t)mt * 9 + r) * 32 + cch) * 3072 + wlane;
            bf16x8 ah[3], al[3];
            #pragma unroll
            for (int i = 0; i < 3; ++i) {
                size_t o = wblk + (size_t)(wm + i * 16) * 8;
                ah[i] = *(const bf16x8*)(Wh + o);
                al[i] = *(const bf16x8*)(Wl + o);
            }
            #pragma unroll
            for (int j = 0; j < 2; ++j) {
                int n = wn + j * 16 + lm;
                int lbase = (((n >> 5) + dy) * 34 + (n & 31) + dx) * XS_STRIDE + koff;
                bf16x8 bh  = *(const bf16x8*)&Xs[lbase];
                bf16x8 blo = *(const bf16x8*)&Xs[XS_H4 + lbase];
                #pragma unroll
                for (int i = 0; i < 3; ++i) {
                    acc[i][j] = __builtin_amdgcn_mfma_f32_16x16x32_bf16(ah[i], bh,  acc[i][j], 0, 0, 0);
                    acc[i][j] = __builtin_amdgcn_mfma_f32_16x16x32_bf16(ah[i], blo, acc[i][j], 0, 0, 0);
                    acc[i][j] = __builtin_amdgcn_mfma_f32_16x16x32_bf16(al[i], bh,  acc[i][j], 0, 0, 0);
                }
            }
        }
    }

    int col = lm, rowb = lq * 4;
    #pragma unroll
    for (int i = 0; i < 3; ++i) {
        int ch4 = mt * 96 + wm + i * 16 + rowb;
        #pragma unroll
        for (int j = 0; j < 2; ++j) {
            int px = rg * 64 + wn + j * 16 + col;
            if (ch4 < 256) {
                u32 p0 = packsplit(acc[i][j][0] + biask[ch4 + 0]);
                u32 p1 = packsplit(acc[i][j][1] + biask[ch4 + 1]);
                u32 p2 = packsplit(acc[i][j][2] + biask[ch4 + 2]);
                u32 p3 = packsplit(acc[i][j][3] + biask[ch4 + 3]);
                *(uint4*)(keyT + ((size_t)b * 1024 + px) * 256 + ch4) = make_uint4(p0, p1, p2, p3);
            } else {
                int cv = ch4 - 256;
                #pragma unroll
                for (int e = 0; e < 4; ++e)
                    valp[((size_t)b * 512 + cv + e) * 1024 + px] = packsplit(acc[i][j][e] + biasv[cv + e]);
            }
        }
    }
}

// ---------------- scores (MFMA): wattn[b][q][m] = (sum_c mk[m][c]*qk[q][c]) / 16 ------
#define AS 40
__global__ __launch_bounds__(256) void k_scores(const u32* __restrict__ qkT,
                                                const u32* __restrict__ mkT,
                                                float* __restrict__ wattn) {
    int mt = blockIdx.x, qt = blockIdx.y, b = blockIdx.z;
    __shared__ bf16 Qh[128][AS], Ql[128][AS], Mh[128][AS], Ml[128][AS];
    int t = threadIdx.x;
    int w_ = t >> 6, l = t & 63;
    int wq = (w_ & 1) * 64, wm = (w_ >> 1) * 64;
    int lm = l & 15, lq = l >> 4, koff = lq * 8;
    int srow = t >> 1, sc4 = (t & 1) * 16;
    const u32* qbase = qkT + ((size_t)b * 1024 + qt * 128 + srow) * 256 + sc4;
    const u32* mbase = mkT + ((size_t)b * 1024 + mt * 128 + srow) * 256 + sc4;
    f32x4 acc[4][4] = {};
    uint4 qv[4], mv[4];
    #pragma unroll
    for (int k = 0; k < 4; ++k) { qv[k] = *(const uint4*)(qbase + k * 4); mv[k] = *(const uint4*)(mbase + k * 4); }
    for (int cc = 0; cc < 8; ++cc) {
        __syncthreads();
        #pragma unroll
        for (int k = 0; k < 4; ++k) {
            uint2 h, lo;
            deint4(qv[k], h, lo);
            *(uint2*)&Qh[srow][sc4 + k * 4] = h;
            *(uint2*)&Ql[srow][sc4 + k * 4] = lo;
            deint4(mv[k], h, lo);
            *(uint2*)&Mh[srow][sc4 + k * 4] = h;
            *(uint2*)&Ml[srow][sc4 + k * 4] = lo;
        }
        __syncthreads();
        if (cc < 7) {
            #pragma unroll
            for (int k = 0; k < 4; ++k) {
                qv[k] = *(const uint4*)(qbase + (cc + 1) * 32 + k * 4);
                mv[k] = *(const uint4*)(mbase + (cc + 1) * 32 + k * 4);
            }
        }
        bf16x8 ah[4], al[4];
        #pragma unroll
        for (int iq = 0; iq < 4; ++iq) {
            ah[iq] = *(const bf16x8*)&Qh[wq + iq * 16 + lm][koff];
            al[iq] = *(const bf16x8*)&Ql[wq + iq * 16 + lm][koff];
        }
        #pragma unroll
        for (int jm = 0; jm < 4; ++jm) {
            bf16x8 bh = *(const bf16x8*)&Mh[wm + jm * 16 + lm][koff];
            bf16x8 bl = *(const bf16x8*)&Ml[wm + jm * 16 + lm][koff];
            #pragma unroll
            for (int iq = 0; iq < 4; ++iq) {
                acc[iq][jm] = __builtin_amdgcn_mfma_f32_16x16x32_bf16(ah[iq], bh, acc[iq][jm], 0, 0, 0);
                acc[iq][jm] = __builtin_amdgcn_mfma_f32_16x16x32_bf16(ah[iq], bl, acc[iq][jm], 0, 0, 0);
                acc[iq][jm] = __builtin_amdgcn_mfma_f32_16x16x32_bf16(al[iq], bh, acc[iq][jm], 0, 0, 0);
            }
        }
    }
    #pragma unroll
    for (int iq = 0; iq < 4; ++iq) {
        int q = qt * 128 + wq + iq * 16 + lq * 4;
        #pragma unroll
        for (int jm = 0; jm < 4; ++jm) {
            int m = mt * 128 + wm + jm * 16 + lm;
            float* wp = wattn + ((size_t)b * 1024 + q) * 1024 + m;
            #pragma unroll
            for (int e = 0; e < 4; ++e)
                wp[(size_t)e * 1024] = acc[iq][jm][e] * 0.0625f;
        }
    }
}

// ---------------- softmax over m; repack row to split-bf16 u32 IN PLACE --------------
__global__ __launch_bounds__(256) void k_softmax(float* __restrict__ wattn) {
    int row = blockIdx.x * 4 + (threadIdx.x >> 6);
    int l = threadIdx.x & 63;
    float* base = wattn + (size_t)row * 1024;
    float4 v[4];
    #pragma unroll
    for (int k = 0; k < 4; ++k) v[k] = *(float4*)(base + l * 4 + k * 256);
    float f[16];
    #pragma unroll
    for (int k = 0; k < 4; ++k) { f[4*k]=v[k].x; f[4*k+1]=v[k].y; f[4*k+2]=v[k].z; f[4*k+3]=v[k].w; }
    float mx = -3.0e38f;
    #pragma unroll
    for (int e = 0; e < 16; ++e) mx = fmaxf(mx, f[e]);
    #pragma unroll
    for (int off = 32; off > 0; off >>= 1) mx = fmaxf(mx, __shfl_xor(mx, off));
    float s = 0.0f;
    #pragma unroll
    for (int e = 0; e < 16; ++e) { f[e] = __expf(f[e] - mx); s += f[e]; }
    #pragma unroll
    for (int off = 32; off > 0; off >>= 1) s += __shfl_xor(s, off);
    float inv = 1.0f / s;
    u32* ub = (u32*)base;
    #pragma unroll
    for (int k = 0; k < 4; ++k) {
        uint4 u = make_uint4(packsplit(f[4*k]   * inv), packsplit(f[4*k+1] * inv),
                             packsplit(f[4*k+2] * inv), packsplit(f[4*k+3] * inv));
        *(uint4*)(ub + l * 4 + k * 256) = u;
    }
}

// ---------------- PV (MFMA): out[b][c][q] = sum_m mval[c][m] * wattn[q][m] ------------
__global__ __launch_bounds__(256) void k_memv(const u32* __restrict__ mvalp,
                                              const u32* __restrict__ wattnp,
                                              float* __restrict__ outp) {
    int ct = blockIdx.x, qt = blockIdx.y, b = blockIdx.z;
    __shared__ bf16 Vh[128][AS], Vl[128][AS], Wh[128][AS], Wl[128][AS];
    int t = threadIdx.x;
    int w_ = t >> 6, l = t & 63;
    int wc = (w_ & 1) * 64, wq = (w_ >> 1) * 64;
    int lm = l & 15, lq = l >> 4, koff = lq * 8;
    int srow = t >> 1, sc4 = (t & 1) * 16;
    const u32* vbase = mvalp  + ((size_t)b * 512  + ct * 128 + srow) * 1024 + sc4;
    const u32* wbase = wattnp + ((size_t)b * 1024 + qt * 128 + srow) * 1024 + sc4;
    f32x4 acc[4][4] = {};
    uint4 vv[4], wv[4];
    #pragma unroll
    for (int k = 0; k < 4; ++k) { vv[k] = *(const uint4*)(vbase + k * 4); wv[k] = *(const uint4*)(wbase + k * 4); }
    for (int mc = 0; mc < 32; ++mc) {
        __syncthreads();
        #pragma unroll
        for (int k = 0; k < 4; ++k) {
            uint2 h, lo;
            deint4(vv[k], h, lo);
            *(uint2*)&Vh[srow][sc4 + k * 4] = h;
            *(uint2*)&Vl[srow][sc4 + k * 4] = lo;
            deint4(wv[k], h, lo);
            *(uint2*)&Wh[srow][sc4 + k * 4] = h;
            *(uint2*)&Wl[srow][sc4 + k * 4] = lo;
        }
        __syncthreads();
        if (mc < 31) {
            #pragma unroll
            for (int k = 0; k < 4; ++k) {
                vv[k] = *(const uint4*)(vbase + (mc + 1) * 32 + k * 4);
                wv[k] = *(const uint4*)(wbase + (mc + 1) * 32 + k * 4);
            }
        }
        bf16x8 ah[4], al[4];
        #pragma unroll
        for (int ic = 0; ic < 4; ++ic) {
            ah[ic] = *(const bf16x8*)&Vh[wc + ic * 16 + lm][koff];
            al[ic] = *(const bf16x8*)&Vl[wc + ic * 16 + lm][koff];
        }
        #pragma unroll
        for (int jq = 0; jq < 4; ++jq) {
            bf16x8 bh = *(const bf16x8*)&Wh[wq + jq * 16 + lm][koff];
            bf16x8 bl = *(const bf16x8*)&Wl[wq + jq * 16 + lm][koff];
            #pragma unroll
            for (int ic = 0; ic < 4; ++ic) {
                acc[ic][jq] = __builtin_amdgcn_mfma_f32_16x16x32_bf16(ah[ic], bh, acc[ic][jq], 0, 0, 0);
                acc[ic][jq] = __builtin_amdgcn_mfma_f32_16x16x32_bf16(ah[ic], bl, acc[ic][jq], 0, 0, 0);
                acc[ic][jq] = __builtin_amdgcn_mfma_f32_16x16x32_bf16(al[ic], bh, acc[ic][jq], 0, 0, 0);
            }
        }
    }
    #pragma unroll
    for (int ic = 0; ic < 4; ++ic) {
        int c = ct * 128 + wc + ic * 16 + lq * 4;
        #pragma unroll
        for (int jq = 0; jq < 4; ++jq) {
            int q = qt * 128 + wq + jq * 16 + lm;
            #pragma unroll
            for (int e = 0; e < 4; ++e)
                outp[((size_t)b * 1024 + c + e) * 1024 + q] = acc[ic][jq][e];
        }
    }
}

extern "C" void kernel_launch(void* const* d_in, const int* in_sizes, int n_in,
                              void* d_out, int out_size, void* d_ws, size_t ws_size,
                              hipStream_t stream) {
    const float* src_temp   = (const float*)d_in[0];
    const float* src_search = (const float*)d_in[1];
    const float* wk_m = (const float*)d_in[2];
    const float* bk_m = (const float*)d_in[3];
    const float* wv_m = (const float*)d_in[4];
    const float* bv_m = (const float*)d_in[5];
    const float* wk_q = (const float*)d_in[6];
    const float* bk_q = (const float*)d_in[7];
    const float* wv_q = (const float*)d_in[8];
    const float* bv_q = (const float*)d_in[9];
    float* out = (float*)d_out;
    char* ws = (char*)d_ws;

    bf16* A    = (bf16*)(ws + OFF_A16HI);          // 32-plane zero target
    bf16* Ah16 = (bf16*)(ws + OFF_A16HI);
    bf16* Al16 = (bf16*)(ws + OFF_A16LO);
    bf16* Ah8  = (bf16*)(ws + OFF_A8HI);
    bf16* Al8  = (bf16*)(ws + OFF_A8LO);
    bf16* W1h  = (bf16*)(ws + OFF_W1HI);
    bf16* W1l  = (bf16*)(ws + OFF_W1LO);
    bf16* W0h  = (bf16*)(ws + OFF_W0HI);
    bf16* W0l  = (bf16*)(ws + OFF_W0LO);
    u32* qkP   = (u32*)(ws + OFF_QKEYT);
    u32* mkP   = (u32*)(ws + OFF_MKEYT);
    u32* mvP   = (u32*)(ws + OFF_MVAL);
    float* wattn = (float*)(ws + OFF_WATTN);
    u32* wattnP  = (u32*)(ws + OFF_WATTN);

    hipLaunchKernelGGL(k_zero, dim3(2112), dim3(256), 0, stream, A);

    // g = 1 (search), fused 16 batches: keys -> qkeyT, values -> d_out ch 512..1023
    hipLaunchKernelGGL(k_wt, dim3(27648), dim3(256), 0, stream, wk_q, wv_q, W1h, W1l);
    hipLaunchKernelGGL(k_transpose, dim3(16, 16, 16), dim3(256), 0, stream,
                       src_search, Ah16, Al16);
    hipLaunchKernelGGL(k_conv16, dim3(1024), dim3(256), 0, stream,
                       Ah16, Al16, W1h, W1l, bk_q, bv_q, qkP, out);

    // g = 0 (temp), 2 x 8 batches: keys -> mkeyT, values -> mval (packed)
    hipLaunchKernelGGL(k_wt, dim3(27648), dim3(256), 0, stream, wk_m, wv_m, W0h, W0l);
    for (int h = 0; h < 2; ++h) {
        hipLaunchKernelGGL(k_transpose, dim3(16, 16, 8), dim3(256), 0, stream,
                           src_temp + (size_t)h * 8 * 1024 * 1024, Ah8, Al8);
        hipLaunchKernelGGL(k_conv8, dim3(1024), dim3(256), 0, stream,
                           Ah8, Al8, W0h, W0l, bk_m, bv_m, mkP, mvP, h * 8);
    }

    hipLaunchKernelGGL(k_scores,  dim3(8, 8, 16), dim3(256), 0, stream, qkP, mkP, wattn);
    hipLaunchKernelGGL(k_softmax, dim3(4096),     dim3(256), 0, stream, wattn);
    hipLaunchKernelGGL(k_memv,    dim3(4, 8, 16), dim3(256), 0, stream, mvP, wattnP, out);
}

// Round 8
// 1530.784 us; speedup vs baseline: 1.0687x; 1.0687x over previous
//
#include <hip/hip_runtime.h>
#include <stdint.h>

typedef __bf16 bf16;
typedef __bf16 bf16x8 __attribute__((ext_vector_type(8)));
typedef float  f32x4  __attribute__((ext_vector_type(4)));
typedef unsigned int u32;

// ---------------- workspace layout (bytes), total = 134,217,728 (128 MiB) ----------
// Phase g1 (search, fused 16-batch conv):
//   A16_hi [16][34][34][1024] bf16 : 0          37,879,808
//   A16_lo                         : 37,879,808 37,879,808  (ends 75,759,616)
//   W1_hi                          : 75,759,616 14,155,776
//   W1_lo                          : 89,915,392 14,155,776  (ends 104,071,168)
//   qkeyT [16][1024px][256c] u32   : 117,440,512 16,777,216 (ends 134,217,728) LIVE->scores
// Phase g0 (temp, 2 x 8-batch conv):
//   A8_hi  [8][34][34][1024] bf16  : 0          18,939,904
//   A8_lo                          : 18,939,904 18,939,904  (ends 37,879,808)
//   W0_hi                          : 37,879,808 14,155,776
//   W0_lo                          : 52,035,584 14,155,776  (ends 66,191,360)
//   mkeyT [16][1024px][256c] u32   : 67,108,864 16,777,216  LIVE->scores
//   mval  [16][512c][1024m] u32    : 83,886,080 33,554,432  (ends 117,440,512) LIVE->memv
// Attention phase:
//   wattn [16][1024q][1024m] f32   : 0          67,108,864  (overlays dead A/W)
#define OFF_A16HI 0ull
#define OFF_A16LO 37879808ull
#define OFF_A8HI  0ull
#define OFF_A8LO  18939904ull
#define OFF_W1HI  75759616ull
#define OFF_W1LO  89915392ull
#define OFF_W0HI  37879808ull
#define OFF_W0LO  52035584ull
#define OFF_MKEYT 67108864ull
#define OFF_MVAL  83886080ull
#define OFF_QKEYT 117440512ull
#define OFF_WATTN 0ull

__device__ __forceinline__ void split(float v, bf16& h, bf16& l) {
    h = (bf16)v;
    l = (bf16)(v - (float)h);
}

__device__ __forceinline__ u32 packsplit(float v) {
    bf16 h = (bf16)v;
    bf16 l = (bf16)(v - (float)h);
    unsigned short hu = __builtin_bit_cast(unsigned short, h);
    unsigned short lu = __builtin_bit_cast(unsigned short, l);
    return (u32)hu | ((u32)lu << 16);
}

// de-interleave 4 packed c's -> 4 hi ushorts + 4 lo ushorts
__device__ __forceinline__ void deint4(const uint4 v, uint2& h, uint2& l) {
    h.x = (v.x & 0xffffu) | (v.y << 16);
    h.y = (v.z & 0xffffu) | (v.w << 16);
    l.x = (v.x >> 16) | (v.y & 0xffff0000u);
    l.y = (v.z >> 16) | (v.w & 0xffff0000u);
}

// global -> LDS DMA, 16B per lane, LDS dest = wave-uniform base + lane*16
__device__ __forceinline__ void gl_lds16(const bf16* g, bf16* l) {
    __builtin_amdgcn_global_load_lds(
        (const __attribute__((address_space(1))) void*)g,
        (__attribute__((address_space(3))) void*)l,
        16, 0, 0);
}

// ---------------- weight transform: fragment-major split ----------------
__global__ __launch_bounds__(256) void k_wt(const float* __restrict__ wk,
                                            const float* __restrict__ wv,
                                            bf16* __restrict__ Wh, bf16* __restrict__ Wl) {
    size_t id = (size_t)blockIdx.x * 256 + threadIdx.x;   // < 7,077,888
    int e = (int)(id & 7);
    size_t t = id >> 3;
    int mm = (int)(t % 96); t /= 96;
    int coff = (int)(t & 3); t >>= 2;
    int cch = (int)(t & 31); t >>= 5;
    int r = (int)(t % 9);
    int mt = (int)(t / 9);
    int m = mt * 96 + mm;
    int c = cch * 32 + coff * 8 + e;
    float v = (m < 256) ? wk[((size_t)m * 1024 + c) * 9 + r]
                        : wv[((size_t)(m - 256) * 1024 + c) * 9 + r];
    bf16 h, l;
    split(v, h, l);
    Wh[id] = h; Wl[id] = l;
}

// ---------------- zero padded borders of 32 A-planes (once) ----------------
__global__ __launch_bounds__(256) void k_zero(bf16* __restrict__ A) {
    int id = blockIdx.x * 256 + threadIdx.x;   // < 540,672
    int oct = id & 127;
    int t = id >> 7;
    int pos = t % 132; t /= 132;               // t = plane 0..31
    int yy, xx;
    if (pos < 34)       { yy = 0;  xx = pos; }
    else if (pos < 68)  { yy = 33; xx = pos - 34; }
    else if (pos < 100) { yy = pos - 68 + 1;  xx = 0; }
    else                { yy = pos - 100 + 1; xx = 33; }
    size_t off = (((size_t)t * 1156) + yy * 34 + xx) * 1024 + (size_t)oct * 8;
    *(uint4*)(A + off) = make_uint4(0u, 0u, 0u, 0u);
}

// ---------------- NCHW f32 -> padded channel-last bf16 hi/lo ----------------
__global__ __launch_bounds__(256) void k_transpose(const float* __restrict__ src,
                                                   bf16* __restrict__ Ah, bf16* __restrict__ Al) {
    int pt = blockIdx.x, ct = blockIdx.y, bl = blockIdx.z;
    __shared__ float tile[64][68];
    int t = threadIdx.x;
    #pragma unroll
    for (int k = 0; k < 4; ++k) {
        int idx = t + 256 * k;          // 0..1023
        int c = idx >> 4, f4 = idx & 15;
        float4 v = *(const float4*)(src + ((size_t)bl * 1024 + ct * 64 + c) * 1024 + pt * 64 + f4 * 4);
        *(float4*)&tile[c][f4 * 4] = v;
    }
    __syncthreads();
    #pragma unroll
    for (int k = 0; k < 2; ++k) {
        int s = t + 256 * k;            // 0..511
        int px = s >> 3, oct = s & 7;
        bf16x8 vh, vl;
        #pragma unroll
        for (int e = 0; e < 8; ++e) {
            bf16 h, l;
            split(tile[oct * 8 + e][px], h, l);
            vh[e] = h; vl[e] = l;
        }
        int pxg = pt * 64 + px;
        int yy = (pxg >> 5) + 1, xx = (pxg & 31) + 1;
        size_t off = (((size_t)bl * 34 + yy) * 34 + xx) * 1024 + ct * 64 + oct * 8;
        *(bf16x8*)(Ah + off) = vh;
        *(bf16x8*)(Al + off) = vl;
    }
}

// LDS conv layout: [row][px34][8 slots x 16B] cells of 128B, LINEAR (global_load_lds
// compatible). Slot j of (row,px) holds c-group (hlk&3) of buffer (hlk>>2), hlk =
// j ^ (px&7): XOR-swizzle applied on the GLOBAL source (rule: linear dest + inverse-
// swizzled source + swizzled read). Read slot for (hl,k) = (hl*4+k) ^ (px&7); bank
// depends only on slot (128B cells) -> 2-way max per 16-lane phase, no VALU writes.

// ---------------- conv g1 (search), fused 16 batches, j=4 ----------------
// 1024 blocks of 256 thr (mt = id&7 -> each XCD L2 holds one mt's weight slice).
// Block: 96 ch x 128 px; staging via global_load_lds (no staging VGPRs -> 4 w/SIMD).
__global__ __launch_bounds__(256) void k_conv16(const bf16* __restrict__ Ah, const bf16* __restrict__ Al,
                                                const bf16* __restrict__ Wh, const bf16* __restrict__ Wl,
                                                const float* __restrict__ biask, const float* __restrict__ biasv,
                                                u32* __restrict__ keyT, float* __restrict__ valf) {
    int id = blockIdx.x;
    int mt = id & 7;
    int r2 = id >> 3;            // 0..127
    int bl = r2 >> 3;            // 0..15 (batch)
    int rg = r2 & 7;             // 0..7 (128-px group)
    int y0 = rg * 4;
    int b = bl;

    __shared__ bf16 Xs[6 * 34 * 64];   // 13,056 el = 26,112 B

    int tid = threadIdx.x;
    int w = tid >> 6, l = tid & 63;
    int wm = (w & 1) * 48, wn = (w >> 1) * 64;
    int lm = l & 15, lq = l >> 4;

    f32x4 acc[3][4] = {};

    const size_t Abase = ((size_t)bl * 34 + y0) * 34 * 1024;
    const size_t wlane = (size_t)lq * 768 + (size_t)lm * 8;

    // per-thread staging source (c-chunk-invariant); LDS dest implicit (lane-linear)
    const bf16* gsrc[7];
    #pragma unroll
    for (int it = 0; it < 7; ++it) {
        int s = tid + 256 * it;          // < 1632 slots of 16B
        if (s < 1632) {
            int row = s / 272;           // 272 = 34*8
            int rem = s - row * 272;
            int px = rem >> 3, j = rem & 7;
            int hlk = j ^ (px & 7);
            const bf16* base = (hlk & 4) ? Al : Ah;
            gsrc[it] = base + Abase + ((size_t)row * 34 + px) * 1024 + (hlk & 3) * 8;
        } else gsrc[it] = nullptr;
    }

    for (int cch = 0; cch < 32; ++cch) {
        int c0 = cch * 32;
        __syncthreads();                 // previous taps' LDS reads complete
        #pragma unroll
        for (int it = 0; it < 7; ++it)
            if (gsrc[it]) gl_lds16(gsrc[it] + c0, &Xs[2048 * it + 512 * w]);
        __syncthreads();                 // vmcnt drained at barrier -> data visible

        #pragma unroll
        for (int r = 0; r < 9; ++r) {
            int dy = r / 3, dx = r % 3;
            size_t wblk = (((size_t)mt * 9 + r) * 32 + cch) * 3072 + wlane;
            bf16x8 ah[3], al[3];
            #pragma unroll
            for (int i = 0; i < 3; ++i) {
                size_t o = wblk + (size_t)(wm + i * 16) * 8;
                ah[i] = *(const bf16x8*)(Wh + o);
                al[i] = *(const bf16x8*)(Wl + o);
            }
            #pragma unroll
            for (int j = 0; j < 4; ++j) {
                int n = wn + j * 16 + lm;
                int px = (n & 31) + dx;
                int row = (n >> 5) + dy;
                int eb = ((row * 34 + px) << 6) + ((lq ^ (px & 7)) << 3);
                bf16x8 bh  = *(const bf16x8*)&Xs[eb];
                bf16x8 blo = *(const bf16x8*)&Xs[eb ^ 32];
                #pragma unroll
                for (int i = 0; i < 3; ++i) {
                    acc[i][j] = __builtin_amdgcn_mfma_f32_16x16x32_bf16(ah[i], bh,  acc[i][j], 0, 0, 0);
                    acc[i][j] = __builtin_amdgcn_mfma_f32_16x16x32_bf16(ah[i], blo, acc[i][j], 0, 0, 0);
                    acc[i][j] = __builtin_amdgcn_mfma_f32_16x16x32_bf16(al[i], bh,  acc[i][j], 0, 0, 0);
                }
            }
        }
    }

    // ---- epilogue: C/D layout col=lane&15, row=(lane>>4)*4+reg ----
    int col = lm, rowb = lq * 4;
    #pragma unroll
    for (int i = 0; i < 3; ++i) {
        int ch4 = mt * 96 + wm + i * 16 + rowb;
        #pragma unroll
        for (int j = 0; j < 4; ++j) {
            int px = rg * 128 + wn + j * 16 + col;
            if (ch4 < 256) {
                u32 p0 = packsplit(acc[i][j][0] + biask[ch4 + 0]);
                u32 p1 = packsplit(acc[i][j][1] + biask[ch4 + 1]);
                u32 p2 = packsplit(acc[i][j][2] + biask[ch4 + 2]);
                u32 p3 = packsplit(acc[i][j][3] + biask[ch4 + 3]);
                *(uint4*)(keyT + ((size_t)b * 1024 + px) * 256 + ch4) = make_uint4(p0, p1, p2, p3);
            } else {
                int cv = ch4 - 256;
                #pragma unroll
                for (int e = 0; e < 4; ++e)
                    valf[((size_t)b * 1024 + 512 + cv + e) * 1024 + px] = acc[i][j][e] + biasv[cv + e];
            }
        }
    }
}

// ---------------- conv g0 (temp), 8 batches, j=2 ----------------
// 1024 blocks (mt = id&7); block 96 ch x 64 px; same global_load_lds staging.
__global__ __launch_bounds__(256) void k_conv8(const bf16* __restrict__ Ah, const bf16* __restrict__ Al,
                                               const bf16* __restrict__ Wh, const bf16* __restrict__ Wl,
                                               const float* __restrict__ biask, const float* __restrict__ biasv,
                                               u32* __restrict__ keyT, u32* __restrict__ valp, int bglob) {
    int id = blockIdx.x;
    int mt = id & 7;
    int r2 = id >> 3;            // 0..127
    int bl = r2 >> 4;            // 0..7
    int rg = r2 & 15;            // 0..15 (64-px group)
    int y0 = rg * 2;
    int b = bglob + bl;

    __shared__ bf16 Xs[4 * 34 * 64];   // 8,704 el = 17,408 B

    int tid = threadIdx.x;
    int w = tid >> 6, l = tid & 63;
    int wm = (w & 1) * 48, wn = (w >> 1) * 32;
    int lm = l & 15, lq = l >> 4;

    f32x4 acc[3][2] = {};

    const size_t Abase = ((size_t)bl * 34 + y0) * 34 * 1024;
    const size_t wlane = (size_t)lq * 768 + (size_t)lm * 8;

    const bf16* gsrc[5];
    #pragma unroll
    for (int it = 0; it < 5; ++it) {
        int s = tid + 256 * it;          // < 1088 slots of 16B
        if (s < 1088) {
            int row = s / 272;
            int rem = s - row * 272;
            int px = rem >> 3, j = rem & 7;
            int hlk = j ^ (px & 7);
            const bf16* base = (hlk & 4) ? Al : Ah;
            gsrc[it] = base + Abase + ((size_t)row * 34 + px) * 1024 + (hlk & 3) * 8;
        } else gsrc[it] = nullptr;
    }

    for (int cch = 0; cch < 32; ++cch) {
        int c0 = cch * 32;
        __syncthreads();
        #pragma unroll
        for (int it = 0; it < 5; ++it)
            if (gsrc[it]) gl_lds16(gsrc[it] + c0, &Xs[2048 * it + 512 * w]);
        __syncthreads();

        #pragma unroll
        for (int r = 0; r < 9; ++r) {
            int dy = r / 3, dx = r % 3;
            size_t wblk = (((size_t)mt * 9 + r) * 32 + cch) * 3072 + wlane;
            bf16x8 ah[3], al[3];
            #pragma unroll
            for (int i = 0; i < 3; ++i) {
                size_t o = wblk + (size_t)(wm + i * 16) * 8;
                ah[i] = *(const bf16x8*)(Wh + o);
                al[i] = *(const bf16x8*)(Wl + o);
            }
            #pragma unroll
            for (int j = 0; j < 2; ++j) {
                int n = wn + j * 16 + lm;
                int px = (n & 31) + dx;
                int row = (n >> 5) + dy;
                int eb = ((row * 34 + px) << 6) + ((lq ^ (px & 7)) << 3);
                bf16x8 bh  = *(const bf16x8*)&Xs[eb];
                bf16x8 blo = *(const bf16x8*)&Xs[eb ^ 32];
                #pragma unroll
                for (int i = 0; i < 3; ++i) {
                    acc[i][j] = __builtin_amdgcn_mfma_f32_16x16x32_bf16(ah[i], bh,  acc[i][j], 0, 0, 0);
                    acc[i][j] = __builtin_amdgcn_mfma_f32_16x16x32_bf16(ah[i], blo, acc[i][j], 0, 0, 0);
                    acc[i][j] = __builtin_amdgcn_mfma_f32_16x16x32_bf16(al[i], bh,  acc[i][j], 0, 0, 0);
                }
            }
        }
    }

    int col = lm, rowb = lq * 4;
    #pragma unroll
    for (int i = 0; i < 3; ++i) {
        int ch4 = mt * 96 + wm + i * 16 + rowb;
        #pragma unroll
        for (int j = 0; j < 2; ++j) {
            int px = rg * 64 + wn + j * 16 + col;
            if (ch4 < 256) {
                u32 p0 = packsplit(acc[i][j][0] + biask[ch4 + 0]);
                u32 p1 = packsplit(acc[i][j][1] + biask[ch4 + 1]);
                u32 p2 = packsplit(acc[i][j][2] + biask[ch4 + 2]);
                u32 p3 = packsplit(acc[i][j][3] + biask[ch4 + 3]);
                *(uint4*)(keyT + ((size_t)b * 1024 + px) * 256 + ch4) = make_uint4(p0, p1, p2, p3);
            } else {
                int cv = ch4 - 256;
                #pragma unroll
                for (int e = 0; e < 4; ++e)
                    valp[((size_t)b * 512 + cv + e) * 1024 + px] = packsplit(acc[i][j][e] + biasv[cv + e]);
            }
        }
    }
}

// ---------------- scores (MFMA): wattn[b][q][m] = (sum_c mk[m][c]*qk[q][c]) / 16 ------
#define AS 40
__global__ __launch_bounds__(256) void k_scores(const u32* __restrict__ qkT,
                                                const u32* __restrict__ mkT,
                                                float* __restrict__ wattn) {
    int mt = blockIdx.x, qt = blockIdx.y, b = blockIdx.z;
    __shared__ bf16 Qh[128][AS], Ql[128][AS], Mh[128][AS], Ml[128][AS];
    int t = threadIdx.x;
    int w_ = t >> 6, l = t & 63;
    int wq = (w_ & 1) * 64, wm = (w_ >> 1) * 64;
    int lm = l & 15, lq = l >> 4, koff = lq * 8;
    int srow = t >> 1, sc4 = (t & 1) * 16;
    const u32* qbase = qkT + ((size_t)b * 1024 + qt * 128 + srow) * 256 + sc4;
    const u32* mbase = mkT + ((size_t)b * 1024 + mt * 128 + srow) * 256 + sc4;
    f32x4 acc[4][4] = {};
    uint4 qv[4], mv[4];
    #pragma unroll
    for (int k = 0; k < 4; ++k) { qv[k] = *(const uint4*)(qbase + k * 4); mv[k] = *(const uint4*)(mbase + k * 4); }
    for (int cc = 0; cc < 8; ++cc) {
        __syncthreads();
        #pragma unroll
        for (int k = 0; k < 4; ++k) {
            uint2 h, lo;
            deint4(qv[k], h, lo);
            *(uint2*)&Qh[srow][sc4 + k * 4] = h;
            *(uint2*)&Ql[srow][sc4 + k * 4] = lo;
            deint4(mv[k], h, lo);
            *(uint2*)&Mh[srow][sc4 + k * 4] = h;
            *(uint2*)&Ml[srow][sc4 + k * 4] = lo;
        }
        __syncthreads();
        if (cc < 7) {
            #pragma unroll
            for (int k = 0; k < 4; ++k) {
                qv[k] = *(const uint4*)(qbase + (cc + 1) * 32 + k * 4);
                mv[k] = *(const uint4*)(mbase + (cc + 1) * 32 + k * 4);
            }
        }
        bf16x8 ah[4], al[4];
        #pragma unroll
        for (int iq = 0; iq < 4; ++iq) {
            ah[iq] = *(const bf16x8*)&Qh[wq + iq * 16 + lm][koff];
            al[iq] = *(const bf16x8*)&Ql[wq + iq * 16 + lm][koff];
        }
        #pragma unroll
        for (int jm = 0; jm < 4; ++jm) {
            bf16x8 bh = *(const bf16x8*)&Mh[wm + jm * 16 + lm][koff];
            bf16x8 bl = *(const bf16x8*)&Ml[wm + jm * 16 + lm][koff];
            #pragma unroll
            for (int iq = 0; iq < 4; ++iq) {
                acc[iq][jm] = __builtin_amdgcn_mfma_f32_16x16x32_bf16(ah[iq], bh, acc[iq][jm], 0, 0, 0);
                acc[iq][jm] = __builtin_amdgcn_mfma_f32_16x16x32_bf16(ah[iq], bl, acc[iq][jm], 0, 0, 0);
                acc[iq][jm] = __builtin_amdgcn_mfma_f32_16x16x32_bf16(al[iq], bh, acc[iq][jm], 0, 0, 0);
            }
        }
    }
    #pragma unroll
    for (int iq = 0; iq < 4; ++iq) {
        int q = qt * 128 + wq + iq * 16 + lq * 4;
        #pragma unroll
        for (int jm = 0; jm < 4; ++jm) {
            int m = mt * 128 + wm + jm * 16 + lm;
            float* wp = wattn + ((size_t)b * 1024 + q) * 1024 + m;
            #pragma unroll
            for (int e = 0; e < 4; ++e)
                wp[(size_t)e * 1024] = acc[iq][jm][e] * 0.0625f;
        }
    }
}

// ---------------- softmax over m; repack row to split-bf16 u32 IN PLACE --------------
__global__ __launch_bounds__(256) void k_softmax(float* __restrict__ wattn) {
    int row = blockIdx.x * 4 + (threadIdx.x >> 6);
    int l = threadIdx.x & 63;
    float* base = wattn + (size_t)row * 1024;
    float4 v[4];
    #pragma unroll
    for (int k = 0; k < 4; ++k) v[k] = *(float4*)(base + l * 4 + k * 256);
    float f[16];
    #pragma unroll
    for (int k = 0; k < 4; ++k) { f[4*k]=v[k].x; f[4*k+1]=v[k].y; f[4*k+2]=v[k].z; f[4*k+3]=v[k].w; }
    float mx = -3.0e38f;
    #pragma unroll
    for (int e = 0; e < 16; ++e) mx = fmaxf(mx, f[e]);
    #pragma unroll
    for (int off = 32; off > 0; off >>= 1) mx = fmaxf(mx, __shfl_xor(mx, off));
    float s = 0.0f;
    #pragma unroll
    for (int e = 0; e < 16; ++e) { f[e] = __expf(f[e] - mx); s += f[e]; }
    #pragma unroll
    for (int off = 32; off > 0; off >>= 1) s += __shfl_xor(s, off);
    float inv = 1.0f / s;
    u32* ub = (u32*)base;
    #pragma unroll
    for (int k = 0; k < 4; ++k) {
        uint4 u = make_uint4(packsplit(f[4*k]   * inv), packsplit(f[4*k+1] * inv),
                             packsplit(f[4*k+2] * inv), packsplit(f[4*k+3] * inv));
        *(uint4*)(ub + l * 4 + k * 256) = u;
    }
}

// ---------------- PV (MFMA): out[b][c][q] = sum_m mval[c][m] * wattn[q][m] ------------
__global__ __launch_bounds__(256) void k_memv(const u32* __restrict__ mvalp,
                                              const u32* __restrict__ wattnp,
                                              float* __restrict__ outp) {
    int ct = blockIdx.x, qt = blockIdx.y, b = blockIdx.z;
    __shared__ bf16 Vh[128][AS], Vl[128][AS], Wh[128][AS], Wl[128][AS];
    int t = threadIdx.x;
    int w_ = t >> 6, l = t & 63;
    int wc = (w_ & 1) * 64, wq = (w_ >> 1) * 64;
    int lm = l & 15, lq = l >> 4, koff = lq * 8;
    int srow = t >> 1, sc4 = (t & 1) * 16;
    const u32* vbase = mvalp  + ((size_t)b * 512  + ct * 128 + srow) * 1024 + sc4;
    const u32* wbase = wattnp + ((size_t)b * 1024 + qt * 128 + srow) * 1024 + sc4;
    f32x4 acc[4][4] = {};
    uint4 vv[4], wv[4];
    #pragma unroll
    for (int k = 0; k < 4; ++k) { vv[k] = *(const uint4*)(vbase + k * 4); wv[k] = *(const uint4*)(wbase + k * 4); }
    for (int mc = 0; mc < 32; ++mc) {
        __syncthreads();
        #pragma unroll
        for (int k = 0; k < 4; ++k) {
            uint2 h, lo;
            deint4(vv[k], h, lo);
            *(uint2*)&Vh[srow][sc4 + k * 4] = h;
            *(uint2*)&Vl[srow][sc4 + k * 4] = lo;
            deint4(wv[k], h, lo);
            *(uint2*)&Wh[srow][sc4 + k * 4] = h;
            *(uint2*)&Wl[srow][sc4 + k * 4] = lo;
        }
        __syncthreads();
        if (mc < 31) {
            #pragma unroll
            for (int k = 0; k < 4; ++k) {
                vv[k] = *(const uint4*)(vbase + (mc + 1) * 32 + k * 4);
                wv[k] = *(const uint4*)(wbase + (mc + 1) * 32 + k * 4);
            }
        }
        bf16x8 ah[4], al[4];
        #pragma unroll
        for (int ic = 0; ic < 4; ++ic) {
            ah[ic] = *(const bf16x8*)&Vh[wc + ic * 16 + lm][koff];
            al[ic] = *(const bf16x8*)&Vl[wc + ic * 16 + lm][koff];
        }
        #pragma unroll
        for (int jq = 0; jq < 4; ++jq) {
            bf16x8 bh = *(const bf16x8*)&Wh[wq + jq * 16 + lm][koff];
            bf16x8 bl = *(const bf16x8*)&Wl[wq + jq * 16 + lm][koff];
            #pragma unroll
            for (int ic = 0; ic < 4; ++ic) {
                acc[ic][jq] = __builtin_amdgcn_mfma_f32_16x16x32_bf16(ah[ic], bh, acc[ic][jq], 0, 0, 0);
                acc[ic][jq] = __builtin_amdgcn_mfma_f32_16x16x32_bf16(ah[ic], bl, acc[ic][jq], 0, 0, 0);
                acc[ic][jq] = __builtin_amdgcn_mfma_f32_16x16x32_bf16(al[ic], bh, acc[ic][jq], 0, 0, 0);
            }
        }
    }
    #pragma unroll
    for (int ic = 0; ic < 4; ++ic) {
        int c = ct * 128 + wc + ic * 16 + lq * 4;
        #pragma unroll
        for (int jq = 0; jq < 4; ++jq) {
            int q = qt * 128 + wq + jq * 16 + lm;
            #pragma unroll
            for (int e = 0; e < 4; ++e)
                outp[((size_t)b * 1024 + c + e) * 1024 + q] = acc[ic][jq][e];
        }
    }
}

extern "C" void kernel_launch(void* const* d_in, const int* in_sizes, int n_in,
                              void* d_out, int out_size, void* d_ws, size_t ws_size,
                              hipStream_t stream) {
    const float* src_temp   = (const float*)d_in[0];
    const float* src_search = (const float*)d_in[1];
    const float* wk_m = (const float*)d_in[2];
    const float* bk_m = (const float*)d_in[3];
    const float* wv_m = (const float*)d_in[4];
    const float* bv_m = (const float*)d_in[5];
    const float* wk_q = (const float*)d_in[6];
    const float* bk_q = (const float*)d_in[7];
    const float* wv_q = (const float*)d_in[8];
    const float* bv_q = (const float*)d_in[9];
    float* out = (float*)d_out;
    char* ws = (char*)d_ws;

    bf16* A    = (bf16*)(ws + OFF_A16HI);          // 32-plane zero target
    bf16* Ah16 = (bf16*)(ws + OFF_A16HI);
    bf16* Al16 = (bf16*)(ws + OFF_A16LO);
    bf16* Ah8  = (bf16*)(ws + OFF_A8HI);
    bf16* Al8  = (bf16*)(ws + OFF_A8LO);
    bf16* W1h  = (bf16*)(ws + OFF_W1HI);
    bf16* W1l  = (bf16*)(ws + OFF_W1LO);
    bf16* W0h  = (bf16*)(ws + OFF_W0HI);
    bf16* W0l  = (bf16*)(ws + OFF_W0LO);
    u32* qkP   = (u32*)(ws + OFF_QKEYT);
    u32* mkP   = (u32*)(ws + OFF_MKEYT);
    u32* mvP   = (u32*)(ws + OFF_MVAL);
    float* wattn = (float*)(ws + OFF_WATTN);
    u32* wattnP  = (u32*)(ws + OFF_WATTN);

    hipLaunchKernelGGL(k_zero, dim3(2112), dim3(256), 0, stream, A);

    // g = 1 (search), fused 16 batches: keys -> qkeyT, values -> d_out ch 512..1023
    hipLaunchKernelGGL(k_wt, dim3(27648), dim3(256), 0, stream, wk_q, wv_q, W1h, W1l);
    hipLaunchKernelGGL(k_transpose, dim3(16, 16, 16), dim3(256), 0, stream,
                       src_search, Ah16, Al16);
    hipLaunchKernelGGL(k_conv16, dim3(1024), dim3(256), 0, stream,
                       Ah16, Al16, W1h, W1l, bk_q, bv_q, qkP, out);

    // g = 0 (temp), 2 x 8 batches: keys -> mkeyT, values -> mval (packed)
    hipLaunchKernelGGL(k_wt, dim3(27648), dim3(256), 0, stream, wk_m, wv_m, W0h, W0l);
    for (int h = 0; h < 2; ++h) {
        hipLaunchKernelGGL(k_transpose, dim3(16, 16, 8), dim3(256), 0, stream,
                           src_temp + (size_t)h * 8 * 1024 * 1024, Ah8, Al8);
        hipLaunchKernelGGL(k_conv8, dim3(1024), dim3(256), 0, stream,
                           Ah8, Al8, W0h, W0l, bk_m, bv_m, mkP, mvP, h * 8);
    }

    hipLaunchKernelGGL(k_scores,  dim3(8, 8, 16), dim3(256), 0, stream, qkP, mkP, wattn);
    hipLaunchKernelGGL(k_softmax, dim3(4096),     dim3(256), 0, stream, wattn);
    hipLaunchKernelGGL(k_memv,    dim3(4, 8, 16), dim3(256), 0, stream, mvP, wattnP, out);
}